// Round 8
// baseline (141.592 us; speedup 1.0000x reference)
//
#include <hip/hip_runtime.h>
#include <cmath>

typedef unsigned short u16;
typedef unsigned int   u32;
typedef __attribute__((ext_vector_type(8))) short short8;
typedef __attribute__((ext_vector_type(4))) float f32x4;

constexpr int BT    = 32;
constexpr int NTOK  = 512;
constexpr int DIM   = 256;
constexpr int HID   = 256;
constexpr int M_ROWS = BT * NTOK;            // 16384
constexpr int HM     = M_ROWS * 32;          // per-head elems in head-major QKV
constexpr size_t TENS = (size_t)M_ROWS * HID; // elems per full tensor
constexpr float LAMBDA_INIT  = 0.35550906759096927f;
constexpr float ONE_MINUS_LI = 0.6444909324090307f;
constexpr float LN_EPS = 1e-5f;
constexpr float QSCALE = 0.36067376022224085f;  // 0.25 * log2(e): fold into Q

// Session lessons:
//  R1: never force tight waves_per_eu (allocator spills). Forcing with 100+
//      VGPR headroom (256,2 here, est ~160 need, cap 256) is OK.
//  R3: no by-ref-capturing lambdas in hot loops (SROA defeat -> scratch).
//  R4: cross-lane type-punned LDS flows need asm volatile("" ::: "memory").
//  R5: attn P-pipeline latency-neutral; attn is issue-bound. Leave it.
//  R6: register-prefetch + full unroll in proj -> live-set blowup -> scratch.
//      Keep proj staging SERIAL with a runtime K-loop.
//  R7: halving proj's A-bytes (xconv) was neutral -> proj is NOT traffic-
//      bound; it's barrier/staging-stall bound at 1024 tiny blocks. This
//      round: 128x64 tile, 512 blocks (2/CU, all resident), 2x MFMA/wave.
constexpr int KCHUNK = 128;

#define MFMA16(a, b, c) __builtin_amdgcn_mfma_f32_16x16x32_bf16((a), (b), (c), 0, 0, 0)
#define LDS_FENCE() asm volatile("" ::: "memory")

__device__ __forceinline__ u16 f2bf(float f) {   // RNE
    u32 u = __float_as_uint(f);
    return (u16)((u + 0x7FFFu + ((u >> 16) & 1u)) >> 16);
}

__device__ __forceinline__ float fexp2(float x) {
#if defined(__has_builtin) && __has_builtin(__builtin_amdgcn_exp2f)
    return __builtin_amdgcn_exp2f(x);
#else
    return exp2f(x);
#endif
}

// pack two f32 -> two bf16 (round-half-up) in one dword: a in low half
__device__ __forceinline__ u32 pack_bf16(float a, float b) {
    u32 ua = __float_as_uint(a) + 0x8000u;
    u32 ub = __float_as_uint(b) + 0x8000u;
    return __builtin_amdgcn_perm(ub, ua, 0x07060302u);
}

// ---------------------------------------------------------------------------
// xconv: x f32 -> bf16 (RNE), row-major unchanged. 8 elems/thread.
// ---------------------------------------------------------------------------
__global__ __launch_bounds__(256) void xconv(const float* __restrict__ x,
                                             u16* __restrict__ Xb) {
    const size_t i = ((size_t)blockIdx.x * 256 + threadIdx.x) * 8;
    const float4* p = (const float4*)(x + i);
    float4 a = p[0], b = p[1];
    uint4 o;
    o.x = (u32)f2bf(a.x) | ((u32)f2bf(a.y) << 16);
    o.y = (u32)f2bf(a.z) | ((u32)f2bf(a.w) << 16);
    o.z = (u32)f2bf(b.x) | ((u32)f2bf(b.y) << 16);
    o.w = (u32)f2bf(b.z) | ((u32)f2bf(b.w) << 16);
    *(uint4*)(Xb + i) = o;
}

// ---------------------------------------------------------------------------
// prep_w: transpose + convert W (f32 [k][n]) -> Wt (bf16 [n][k]), 3 matrices
// ---------------------------------------------------------------------------
__global__ __launch_bounds__(256) void prep_w(const float* __restrict__ Wq,
                                              const float* __restrict__ Wk,
                                              const float* __restrict__ Wv,
                                              u16* __restrict__ Wt) {
    const float* W = (blockIdx.z == 0) ? Wq : (blockIdx.z == 1) ? Wk : Wv;
    u16* dst = Wt + (size_t)blockIdx.z * 65536;
    __shared__ float T[64][65];
    const int k0 = blockIdx.x * 64, n0 = blockIdx.y * 64;
    const int tr = threadIdx.x >> 4;
    const int tc = threadIdx.x & 15;
    #pragma unroll
    for (int i = 0; i < 4; ++i) {
        int row = tr + i * 16;
        float4 v = *(const float4*)&W[(size_t)(k0 + row) * HID + n0 + tc * 4];
        T[row][tc * 4 + 0] = v.x; T[row][tc * 4 + 1] = v.y;
        T[row][tc * 4 + 2] = v.z; T[row][tc * 4 + 3] = v.w;
    }
    __syncthreads();
    #pragma unroll
    for (int i = 0; i < 4; ++i) {
        int n = tr + i * 16;
        int k4 = tc * 4;
        uint2 pk;
        pk.x = (u32)f2bf(T[k4 + 0][n]) | ((u32)f2bf(T[k4 + 1][n]) << 16);
        pk.y = (u32)f2bf(T[k4 + 2][n]) | ((u32)f2bf(T[k4 + 3][n]) << 16);
        *(uint2*)&dst[(size_t)(n0 + n) * DIM + k0 + k4] = pk;
    }
}

// ---------------------------------------------------------------------------
// proj: fused QKV GEMM. Tile 128x64 (M x N), BK=64, serial staging, runtime
// K-loop (no prefetch/unroll -- R6 lesson). 4 waves, each 32 rows x 64 cols
// per z: acc[3][8] f32x4 (96 VGPR). 512 blocks = 2/CU, all co-resident.
// Writes head-major bf16 [h][row][32]; Q scaled by QSCALE.
// ---------------------------------------------------------------------------
__global__ __launch_bounds__(256, 2) void proj_kernel(
    const u16* __restrict__ Xb, const u16* __restrict__ Wt,
    u16* __restrict__ Qh, u16* __restrict__ Kh, u16* __restrict__ Vh)
{
    __shared__ u16 As[128 * 72];     // [m][k], stride 72: 18.0KB
    __shared__ u16 Bs[3][64 * 72];   // [n][k] per z: 27.0KB

    const int tid  = threadIdx.x;
    const int m0   = blockIdx.x * 128;
    const int n0   = blockIdx.y * 64;
    const int lane = tid & 63;
    const int wv   = tid >> 6;
    const int q16  = lane & 15;
    const int quad = lane >> 4;
    const int mw   = wv * 32;         // wave's 32-row stripe

    const int sr2 = tid >> 1;         // 0..127 A-staging row
    const int sc2 = (tid & 1) * 32;   // elem offset (32 elems = 64B half-row)
    const int sr  = tid >> 2;         // 0..63  B-staging row
    const int sc  = (tid & 3) * 16;   // 0,16,32,48

    f32x4 acc[3][8];                  // [z][mi*4+nf]
    #pragma unroll
    for (int z = 0; z < 3; ++z)
        #pragma unroll
        for (int t = 0; t < 8; ++t)
            acc[z][t] = (f32x4){0.f, 0.f, 0.f, 0.f};

    for (int kk = 0; kk < DIM; kk += 64) {
        // A tile: 128 rows x 64 k, 2 threads/row, 4 uint4 each
        {
            const uint4* xs = (const uint4*)&Xb[(size_t)(m0 + sr2) * DIM + kk + sc2];
            uint4* d = (uint4*)&As[sr2 * 72 + sc2];
            d[0] = xs[0]; d[1] = xs[1]; d[2] = xs[2]; d[3] = xs[3];
        }
        // B tiles: 3 x 64 rows x 64 k, 2 uint4 each
        #pragma unroll
        for (int z = 0; z < 3; ++z) {
            const uint4* ws4 = (const uint4*)&Wt[(size_t)z * 65536 + (size_t)(n0 + sr) * DIM + kk + sc];
            *(uint4*)&Bs[z][sr * 72 + sc]     = ws4[0];
            *(uint4*)&Bs[z][sr * 72 + sc + 8] = ws4[1];
        }
        __syncthreads();
        #pragma unroll
        for (int kc = 0; kc < 2; ++kc) {
            short8 a0 = *(const short8*)&As[(mw +      q16) * 72 + kc * 32 + quad * 8];
            short8 a1 = *(const short8*)&As[(mw + 16 + q16) * 72 + kc * 32 + quad * 8];
            #pragma unroll
            for (int z = 0; z < 3; ++z) {
                #pragma unroll
                for (int nf = 0; nf < 4; ++nf) {
                    short8 b = *(const short8*)&Bs[z][(nf * 16 + q16) * 72 + kc * 32 + quad * 8];
                    acc[z][nf]     = MFMA16(a0, b, acc[z][nf]);
                    acc[z][4 + nf] = MFMA16(a1, b, acc[z][4 + nf]);
                }
            }
        }
        __syncthreads();
    }

    // epilogue: head-major store. C/D: col=lane&15, row=quad*4+reg
    #pragma unroll
    for (int z = 0; z < 3; ++z) {
        u16* C = (z == 0) ? Qh : (z == 1) ? Kh : Vh;
        const float s = (z == 0) ? QSCALE : 1.0f;
        #pragma unroll
        for (int mi = 0; mi < 2; ++mi) {
            #pragma unroll
            for (int nf = 0; nf < 4; ++nf) {
                const int hcol = (n0 >> 5) + (nf >> 1);
                const int off  = (nf & 1) * 16;
                u16* base = C + (size_t)hcol * HM;
                const f32x4 v = acc[z][mi * 4 + nf];
                #pragma unroll
                for (int r = 0; r < 4; ++r) {
                    const int row = m0 + mw + mi * 16 + quad * 4 + r;
                    base[(size_t)row * 32 + off + q16] = f2bf(v[r] * s);
                }
            }
        }
    }
}

// ---------------------------------------------------------------------------
// attn: transposed-QK MFMA attention + diff combine + LayerNorm.
// (byte-identical to round 5/7)
// ---------------------------------------------------------------------------
__global__ __launch_bounds__(256, 3) void attn_kernel(
    const u16* __restrict__ Qh, const u16* __restrict__ Kh, const u16* __restrict__ Vh,
    const float* __restrict__ lq1, const float* __restrict__ lk1,
    const float* __restrict__ lq2, const float* __restrict__ lk2,
    const float* __restrict__ gamma, const float* __restrict__ beta,
    float* __restrict__ out)
{
    constexpr int VSTR = KCHUNK + 8;
    constexpr int NKC  = KCHUNK / 32;        // 4 kc steps per chunk

    __shared__ u16 Ks[KCHUNK * 40];          // [key][dim] 10.0KB
    __shared__ u16 Vts[32 * VSTR];           // [dim][key]  8.5KB
    __shared__ u16 Pbuf[4][2][2][16 * 40];   // [wave][parity][matrix][q][key] 20.5KB

    const int qh  = blockIdx.x;   // 0..3 (128 q rows each)
    const int h   = blockIdx.y;   // 0..7
    const int bt  = blockIdx.z;   // 0..31
    const int tid = threadIdx.x;
    const int lane = tid & 63;
    const int wv   = tid >> 6;
    const int q16  = lane & 15;
    const int quad = lane >> 4;

    // lambda scalar (uniform path)
    float sa = 0.f, sb = 0.f;
    #pragma unroll
    for (int d = 0; d < 16; ++d) { sa += lq1[d] * lk1[d]; sb += lq2[d] * lk2[d]; }
    const float lam = __expf(sa) - __expf(sb) + LAMBDA_INIT;

    // Q B-fragments for this wave's two 16-row q blocks (pre-scaled at proj)
    short8 qv[2];
    #pragma unroll
    for (int qbi = 0; qbi < 2; ++qbi) {
        const int qrow = bt * NTOK + qh * 128 + (qbi * 4 + wv) * 16 + q16;
        qv[qbi] = *(const short8*)(Qh + (size_t)h * HM + (size_t)qrow * 32 + quad * 8);
    }

    const short8 z8 = {0, 0, 0, 0, 0, 0, 0, 0};
    const f32x4  z4 = {0.f, 0.f, 0.f, 0.f};

    f32x4 o1lo[2], o1hi[2], o2lo[2], o2hi[2];
    #pragma unroll
    for (int qbi = 0; qbi < 2; ++qbi) {
        o1lo[qbi] = z4; o1hi[qbi] = z4; o2lo[qbi] = z4; o2hi[qbi] = z4;
    }
    float l1[2] = {0.f, 0.f}, l2[2] = {0.f, 0.f};

    for (int chunk = 0; chunk < NTOK / KCHUNK; ++chunk) {
        if (chunk) __syncthreads();   // drain previous chunk's LDS reads
        // ---- stage K chunk: 128 rows, 2 threads per row (32B each, coalesced) ----
        {
            const int key  = tid >> 1;
            const int half = (tid & 1) * 16;   // u16 offset within 32-dim row
            const uint4* src = (const uint4*)(Kh + (size_t)h * HM +
                                (size_t)(bt * NTOK + chunk * KCHUNK + key) * 32 + half);
            uint4* dst = (uint4*)&Ks[key * 40 + half];
            dst[0] = src[0]; dst[1] = src[1];
        }
        // ---- stage V chunk transposed: threads 0..63, 2 keys each ----
        if (tid < KCHUNK / 2) {
            const int j0 = tid * 2;
            const u16* v0 = Vh + (size_t)h * HM + (size_t)(bt * NTOK + chunk * KCHUNK + j0) * 32;
            union U { uint4 q[4]; u32 w[16]; } ra, rb;
            #pragma unroll
            for (int i = 0; i < 4; ++i) {
                ra.q[i] = ((const uint4*)v0)[i];
                rb.q[i] = ((const uint4*)(v0 + 32))[i];
            }
            #pragma unroll
            for (int w = 0; w < 16; ++w) {
                u32 lo = __builtin_amdgcn_perm(rb.w[w], ra.w[w], 0x05040100u); // dim 2w
                u32 hi = __builtin_amdgcn_perm(rb.w[w], ra.w[w], 0x07060302u); // dim 2w+1
                *(u32*)&Vts[(2 * w)     * VSTR + j0] = lo;
                *(u32*)&Vts[(2 * w + 1) * VSTR + j0] = hi;
            }
        }
        __syncthreads();

        #pragma unroll
        for (int qbi = 0; qbi < 2; ++qbi) {
            const short8 A1 = (lane < 32) ? qv[qbi] : z8;  // dims 0..15
            const short8 A2 = (lane < 32) ? z8 : qv[qbi];  // dims 16..31

            #pragma unroll
            for (int kc = 0; kc < NKC; ++kc) {
                // ---- QK phase for step kc -> Pbuf[wv][kc&1] (inline) ----
                #pragma unroll
                for (int sub = 0; sub < 2; ++sub) {
                    const int key0 = kc * 32 + sub * 16;
                    short8 kf = *(const short8*)&Ks[(key0 + q16) * 40 + quad * 8];
                    // S^T: D[key=quad*4+r][q=q16]
                    f32x4 s1 = MFMA16(kf, A1, z4);
                    f32x4 s2 = MFMA16(kf, A2, z4);
                    float p0 = fexp2(s1[0]), p1 = fexp2(s1[1]);
                    float p2 = fexp2(s1[2]), p3 = fexp2(s1[3]);
                    l1[qbi] += (p0 + p1) + (p2 + p3);
                    uint2 w1; w1.x = pack_bf16(p0, p1); w1.y = pack_bf16(p2, p3);
                    *(uint2*)&Pbuf[wv][kc & 1][0][q16 * 40 + sub * 16 + quad * 4] = w1;
                    float r0 = fexp2(s2[0]), r1 = fexp2(s2[1]);
                    float r2 = fexp2(s2[2]), r3 = fexp2(s2[3]);
                    l2[qbi] += (r0 + r1) + (r2 + r3);
                    uint2 w2; w2.x = pack_bf16(r0, r1); w2.y = pack_bf16(r2, r3);
                    *(uint2*)&Pbuf[wv][kc & 1][1][q16 * 40 + sub * 16 + quad * 4] = w2;
                }
                LDS_FENCE();   // pin: QK writes of kc stay above PV reads below
                // ---- PV phase for step kc-1 <- Pbuf[wv][(kc-1)&1] (inline) ----
                if (kc > 0) {
                    const int pk = kc - 1;
                    const int pb = (kc - 1) & 1;
                    short8 pf1 = *(const short8*)&Pbuf[wv][pb][0][q16 * 40 + quad * 8];
                    short8 pf2 = *(const short8*)&Pbuf[wv][pb][1][q16 * 40 + quad * 8];
                    short8 vlo = *(const short8*)&Vts[q16        * VSTR + pk * 32 + quad * 8];
                    short8 vhi = *(const short8*)&Vts[(16 + q16) * VSTR + pk * 32 + quad * 8];
                    o1lo[qbi] = MFMA16(pf1, vlo, o1lo[qbi]);
                    o1hi[qbi] = MFMA16(pf1, vhi, o1hi[qbi]);
                    o2lo[qbi] = MFMA16(pf2, vlo, o2lo[qbi]);
                    o2hi[qbi] = MFMA16(pf2, vhi, o2hi[qbi]);
                }
                LDS_FENCE();   // pin: PV reads of kc-1 stay above QK writes of kc+1
            }
            // ---- PV tail for step NKC-1 (inline) ----
            {
                const int pk = NKC - 1;
                const int pb = (NKC - 1) & 1;
                short8 pf1 = *(const short8*)&Pbuf[wv][pb][0][q16 * 40 + quad * 8];
                short8 pf2 = *(const short8*)&Pbuf[wv][pb][1][q16 * 40 + quad * 8];
                short8 vlo = *(const short8*)&Vts[q16        * VSTR + pk * 32 + quad * 8];
                short8 vhi = *(const short8*)&Vts[(16 + q16) * VSTR + pk * 32 + quad * 8];
                o1lo[qbi] = MFMA16(pf1, vlo, o1lo[qbi]);
                o1hi[qbi] = MFMA16(pf1, vhi, o1hi[qbi]);
                o2lo[qbi] = MFMA16(pf2, vlo, o2lo[qbi]);
                o2hi[qbi] = MFMA16(pf2, vhi, o2hi[qbi]);
            }
            LDS_FENCE();       // pin: tail reads stay above next qbi's QK writes
        }
    }

    // ---- epilogue: softmax-normalize, diff combine, LayerNorm(32), store ----
    const float g_lo = gamma[q16],      g_hi = gamma[16 + q16];
    const float b_lo = beta[q16],       b_hi = beta[16 + q16];

    #pragma unroll
    for (int qbi = 0; qbi < 2; ++qbi) {
        float a = l1[qbi], b = l2[qbi];
        a += __shfl_xor(a, 16); a += __shfl_xor(a, 32);
        b += __shfl_xor(b, 16); b += __shfl_xor(b, 32);
        const float inv1 = 1.0f / a;    // valid for q = q16 (lanes 0..15 canonical)
        const float inv2 = 1.0f / b;
        #pragma unroll
        for (int r = 0; r < 4; ++r) {
            const float i1 = __shfl(inv1, quad * 4 + r);
            const float i2 = __shfl(inv2, quad * 4 + r);
            const float ylo = o1lo[qbi][r] * i1 - lam * (o2lo[qbi][r] * i2);
            const float yhi = o1hi[qbi][r] * i1 - lam * (o2hi[qbi][r] * i2);

            float s  = ylo + yhi;
            float s2 = ylo * ylo + yhi * yhi;
            #pragma unroll
            for (int off = 1; off < 16; off <<= 1) {
                s  += __shfl_xor(s,  off);
                s2 += __shfl_xor(s2, off);
            }
            const float mu   = s * (1.0f / 32.0f);
            const float var  = s2 * (1.0f / 32.0f) - mu * mu;
            const float rstd = rsqrtf(var + LN_EPS);

            const int row = bt * NTOK + qh * 128 + (qbi * 4 + wv) * 16 + quad * 4 + r;
            float* orow = out + (size_t)row * HID + h * 32;
            orow[q16]      = ((ylo - mu) * rstd * g_lo + b_lo) * ONE_MINUS_LI;
            orow[16 + q16] = ((yhi - mu) * rstd * g_hi + b_hi) * ONE_MINUS_LI;
        }
    }
}

// ---------------------------------------------------------------------------
extern "C" void kernel_launch(void* const* d_in, const int* in_sizes, int n_in,
                              void* d_out, int out_size, void* d_ws, size_t ws_size,
                              hipStream_t stream) {
    const float* x   = (const float*)d_in[0];
    const float* Wq  = (const float*)d_in[1];
    const float* Wk  = (const float*)d_in[2];
    const float* Wv  = (const float*)d_in[3];
    const float* lq1 = (const float*)d_in[4];
    const float* lk1 = (const float*)d_in[5];
    const float* lq2 = (const float*)d_in[6];
    const float* lk2 = (const float*)d_in[7];
    const float* gam = (const float*)d_in[8];
    const float* bet = (const float*)d_in[9];
    float* out = (float*)d_out;

    u16* ws = (u16*)d_ws;
    u16* Wt = ws;                 // 3 * 65536
    u16* Qh = Wt + 3 * 65536;     // head-major [8][16384][32]
    u16* Kh = Qh + TENS;
    u16* Vh = Kh + TENS;
    u16* Xb = Vh + TENS;          // bf16 x, row-major [16384][256]

    hipLaunchKernelGGL(xconv, dim3(M_ROWS * DIM / (256 * 8)), dim3(256), 0, stream, x, Xb);
    hipLaunchKernelGGL(prep_w, dim3(4, 4, 3), dim3(256), 0, stream, Wq, Wk, Wv, Wt);
    hipLaunchKernelGGL(proj_kernel, dim3(M_ROWS / 128, HID / 64), dim3(256), 0, stream,
                       Xb, Wt, Qh, Kh, Vh);
    hipLaunchKernelGGL(attn_kernel, dim3(4, 8, 32), dim3(256), 0, stream,
                       Qh, Kh, Vh, lq1, lk1, lq2, lk2, gam, bet, out);
}

// Round 10
// 132.211 us; speedup vs baseline: 1.0710x; 1.0710x over previous
//
#include <hip/hip_runtime.h>
#include <cmath>

typedef unsigned short u16;
typedef unsigned int   u32;
typedef __attribute__((ext_vector_type(8))) short short8;
typedef __attribute__((ext_vector_type(4))) float f32x4;

constexpr int BT    = 32;
constexpr int NTOK  = 512;
constexpr int DIM   = 256;
constexpr int HID   = 256;
constexpr int M_ROWS = BT * NTOK;            // 16384
constexpr int HM     = M_ROWS * 32;          // per-head elems in head-major QKV
constexpr size_t TENS = (size_t)M_ROWS * HID; // elems per full tensor
constexpr float LAMBDA_INIT  = 0.35550906759096927f;
constexpr float ONE_MINUS_LI = 0.6444909324090307f;
constexpr float LN_EPS = 1e-5f;
constexpr float QSCALE = 0.36067376022224085f;  // 0.25 * log2(e): fold into Q

// Session lessons:
//  R1: never force tight waves_per_eu (allocator spills).
//  R3: no by-ref-capturing lambdas in hot loops (SROA defeat -> scratch).
//  R4: cross-lane type-punned LDS flows need asm volatile("" ::: "memory").
//  R5: attn P-pipeline latency-neutral; attn issue/latency-bound.
//  R6/R8: proj staging/tiling changes all neutral-negative; proj structure
//      is at its plateau for this decomposition.
//  R7: halving proj A-bytes neutral -> not traffic-bound.
//  R9: register async-STAGE in attn failed correctness (unexplained,
//      deterministic); direction abandoned -- revert to R5-proven staging.
//  R10 (this): T5 s_setprio(1) around attn MFMA clusters only (measured
//      attn precedent +4-7%; GEMM lockstep was neutral so proj untouched).
constexpr int KCHUNK = 128;

#define MFMA16(a, b, c) __builtin_amdgcn_mfma_f32_16x16x32_bf16((a), (b), (c), 0, 0, 0)
#define LDS_FENCE() asm volatile("" ::: "memory")

__device__ __forceinline__ u16 f2bf(float f) {   // RNE
    u32 u = __float_as_uint(f);
    return (u16)((u + 0x7FFFu + ((u >> 16) & 1u)) >> 16);
}

__device__ __forceinline__ float fexp2(float x) {
#if defined(__has_builtin) && __has_builtin(__builtin_amdgcn_exp2f)
    return __builtin_amdgcn_exp2f(x);
#else
    return exp2f(x);
#endif
}

// pack two f32 -> two bf16 (round-half-up) in one dword: a in low half
__device__ __forceinline__ u32 pack_bf16(float a, float b) {
    u32 ua = __float_as_uint(a) + 0x8000u;
    u32 ub = __float_as_uint(b) + 0x8000u;
    return __builtin_amdgcn_perm(ub, ua, 0x07060302u);
}

// ---------------------------------------------------------------------------
// prep_w: transpose + convert W (f32 [k][n]) -> Wt (bf16 [n][k]), 3 matrices
// ---------------------------------------------------------------------------
__global__ __launch_bounds__(256) void prep_w(const float* __restrict__ Wq,
                                              const float* __restrict__ Wk,
                                              const float* __restrict__ Wv,
                                              u16* __restrict__ Wt) {
    const float* W = (blockIdx.z == 0) ? Wq : (blockIdx.z == 1) ? Wk : Wv;
    u16* dst = Wt + (size_t)blockIdx.z * 65536;
    __shared__ float T[64][65];
    const int k0 = blockIdx.x * 64, n0 = blockIdx.y * 64;
    const int tr = threadIdx.x >> 4;
    const int tc = threadIdx.x & 15;
    #pragma unroll
    for (int i = 0; i < 4; ++i) {
        int row = tr + i * 16;
        float4 v = *(const float4*)&W[(size_t)(k0 + row) * HID + n0 + tc * 4];
        T[row][tc * 4 + 0] = v.x; T[row][tc * 4 + 1] = v.y;
        T[row][tc * 4 + 2] = v.z; T[row][tc * 4 + 3] = v.w;
    }
    __syncthreads();
    #pragma unroll
    for (int i = 0; i < 4; ++i) {
        int n = tr + i * 16;
        int k4 = tc * 4;
        uint2 pk;
        pk.x = (u32)f2bf(T[k4 + 0][n]) | ((u32)f2bf(T[k4 + 1][n]) << 16);
        pk.y = (u32)f2bf(T[k4 + 2][n]) | ((u32)f2bf(T[k4 + 3][n]) << 16);
        *(uint2*)&dst[(size_t)(n0 + n) * DIM + k0 + k4] = pk;
    }
}

// ---------------------------------------------------------------------------
// proj: fused QKV GEMM (exact R5-proven structure). Stages x tile (f32->bf16
// inline), multiplies by all 3 weights. Tile 64x64, BK=64, 4 waves each
// 32x32. Writes head-major bf16 [h][row][32]; Q scaled by QSCALE.
// ---------------------------------------------------------------------------
__global__ __launch_bounds__(256, 3) void proj_kernel(
    const float* __restrict__ x, const u16* __restrict__ Wt,
    u16* __restrict__ Qh, u16* __restrict__ Kh, u16* __restrict__ Vh)
{
    __shared__ u16 As[64 * 72];      // [m][k], stride 72 (144B, 16B aligned)
    __shared__ u16 Bs[3][64 * 72];   // [n][k] per z

    const int tid  = threadIdx.x;
    const int m0   = blockIdx.x * 64;
    const int n0   = blockIdx.y * 64;
    const int lane = tid & 63;
    const int wv   = tid >> 6;
    const int q16  = lane & 15;
    const int quad = lane >> 4;
    const int mw   = (wv >> 1) * 32;
    const int nw   = (wv & 1) * 32;

    const int sr = tid >> 2;          // 0..63 staging row
    const int sc = (tid & 3) * 16;    // 0,16,32,48 (u16 offset within 64-k)

    f32x4 acc[3][4];
    #pragma unroll
    for (int z = 0; z < 3; ++z)
        #pragma unroll
        for (int t = 0; t < 4; ++t)
            acc[z][t] = (f32x4){0.f, 0.f, 0.f, 0.f};

    for (int kk = 0; kk < DIM; kk += 64) {
        // A tile: load f32, convert to bf16
        {
            const float4* xs = (const float4*)&x[(size_t)(m0 + sr) * DIM + kk + sc];
            float4 g0 = xs[0], g1 = xs[1], g2 = xs[2], g3 = xs[3];
            uint4 o0, o1;
            o0.x = (u32)f2bf(g0.x) | ((u32)f2bf(g0.y) << 16);
            o0.y = (u32)f2bf(g0.z) | ((u32)f2bf(g0.w) << 16);
            o0.z = (u32)f2bf(g1.x) | ((u32)f2bf(g1.y) << 16);
            o0.w = (u32)f2bf(g1.z) | ((u32)f2bf(g1.w) << 16);
            o1.x = (u32)f2bf(g2.x) | ((u32)f2bf(g2.y) << 16);
            o1.y = (u32)f2bf(g2.z) | ((u32)f2bf(g2.w) << 16);
            o1.z = (u32)f2bf(g3.x) | ((u32)f2bf(g3.y) << 16);
            o1.w = (u32)f2bf(g3.z) | ((u32)f2bf(g3.w) << 16);
            *(uint4*)&As[sr * 72 + sc]     = o0;
            *(uint4*)&As[sr * 72 + sc + 8] = o1;
        }
        // B tiles (already bf16 in Wt)
        #pragma unroll
        for (int z = 0; z < 3; ++z) {
            const uint4* ws4 = (const uint4*)&Wt[(size_t)z * 65536 + (size_t)(n0 + sr) * DIM + kk + sc];
            *(uint4*)&Bs[z][sr * 72 + sc]     = ws4[0];
            *(uint4*)&Bs[z][sr * 72 + sc + 8] = ws4[1];
        }
        __syncthreads();
        #pragma unroll
        for (int kc = 0; kc < 2; ++kc) {
            short8 a0 = *(const short8*)&As[(mw +      q16) * 72 + kc * 32 + quad * 8];
            short8 a1 = *(const short8*)&As[(mw + 16 + q16) * 72 + kc * 32 + quad * 8];
            #pragma unroll
            for (int z = 0; z < 3; ++z) {
                short8 b0 = *(const short8*)&Bs[z][(nw +      q16) * 72 + kc * 32 + quad * 8];
                short8 b1 = *(const short8*)&Bs[z][(nw + 16 + q16) * 72 + kc * 32 + quad * 8];
                acc[z][0] = MFMA16(a0, b0, acc[z][0]);
                acc[z][1] = MFMA16(a0, b1, acc[z][1]);
                acc[z][2] = MFMA16(a1, b0, acc[z][2]);
                acc[z][3] = MFMA16(a1, b1, acc[z][3]);
            }
        }
        __syncthreads();
    }

    // epilogue: head-major store. C/D: col=lane&15, row=quad*4+reg
    const int hcol = (n0 + nw) >> 5;     // (n0+nw) is a multiple of 32
    #pragma unroll
    for (int z = 0; z < 3; ++z) {
        u16* C = (z == 0) ? Qh : (z == 1) ? Kh : Vh;
        u16* base = C + (size_t)hcol * HM;
        const float s = (z == 0) ? QSCALE : 1.0f;
        #pragma unroll
        for (int r = 0; r < 4; ++r) {
            const int row = m0 + mw + quad * 4 + r;
            base[(size_t)row * 32 + q16]             = f2bf(acc[z][0][r] * s);
            base[(size_t)row * 32 + q16 + 16]        = f2bf(acc[z][1][r] * s);
            base[(size_t)(row + 16) * 32 + q16]      = f2bf(acc[z][2][r] * s);
            base[(size_t)(row + 16) * 32 + q16 + 16] = f2bf(acc[z][3][r] * s);
        }
    }
}

// ---------------------------------------------------------------------------
// attn: transposed-QK MFMA attention + diff combine + LayerNorm.
// Exact R5-proven structure (132.7us, passed) + T5 s_setprio(1) wrapped
// around the MFMA clusters: waves in the MFMA-entering phase get scheduler
// priority over waves issuing exp2/VALU, keeping the matrix pipe fed.
// ---------------------------------------------------------------------------
__global__ __launch_bounds__(256, 3) void attn_kernel(
    const u16* __restrict__ Qh, const u16* __restrict__ Kh, const u16* __restrict__ Vh,
    const float* __restrict__ lq1, const float* __restrict__ lk1,
    const float* __restrict__ lq2, const float* __restrict__ lk2,
    const float* __restrict__ gamma, const float* __restrict__ beta,
    float* __restrict__ out)
{
    constexpr int VSTR = KCHUNK + 8;
    constexpr int NKC  = KCHUNK / 32;        // 4 kc steps per chunk

    __shared__ u16 Ks[KCHUNK * 40];          // [key][dim] 10.0KB
    __shared__ u16 Vts[32 * VSTR];           // [dim][key]  8.5KB
    __shared__ u16 Pbuf[4][2][2][16 * 40];   // [wave][parity][matrix][q][key] 20.5KB

    const int qh  = blockIdx.x;   // 0..3 (128 q rows each)
    const int h   = blockIdx.y;   // 0..7
    const int bt  = blockIdx.z;   // 0..31
    const int tid = threadIdx.x;
    const int lane = tid & 63;
    const int wv   = tid >> 6;
    const int q16  = lane & 15;
    const int quad = lane >> 4;

    // lambda scalar (uniform path)
    float sa = 0.f, sb = 0.f;
    #pragma unroll
    for (int d = 0; d < 16; ++d) { sa += lq1[d] * lk1[d]; sb += lq2[d] * lk2[d]; }
    const float lam = __expf(sa) - __expf(sb) + LAMBDA_INIT;

    // Q B-fragments for this wave's two 16-row q blocks (pre-scaled at proj)
    short8 qv[2];
    #pragma unroll
    for (int qbi = 0; qbi < 2; ++qbi) {
        const int qrow = bt * NTOK + qh * 128 + (qbi * 4 + wv) * 16 + q16;
        qv[qbi] = *(const short8*)(Qh + (size_t)h * HM + (size_t)qrow * 32 + quad * 8);
    }

    const short8 z8 = {0, 0, 0, 0, 0, 0, 0, 0};
    const f32x4  z4 = {0.f, 0.f, 0.f, 0.f};

    f32x4 o1lo[2], o1hi[2], o2lo[2], o2hi[2];
    #pragma unroll
    for (int qbi = 0; qbi < 2; ++qbi) {
        o1lo[qbi] = z4; o1hi[qbi] = z4; o2lo[qbi] = z4; o2hi[qbi] = z4;
    }
    float l1[2] = {0.f, 0.f}, l2[2] = {0.f, 0.f};

    for (int chunk = 0; chunk < NTOK / KCHUNK; ++chunk) {
        if (chunk) __syncthreads();   // drain previous chunk's LDS reads
        // ---- stage K chunk: 128 rows, 2 threads per row (32B each, coalesced) ----
        {
            const int key  = tid >> 1;
            const int half = (tid & 1) * 16;   // u16 offset within 32-dim row
            const uint4* src = (const uint4*)(Kh + (size_t)h * HM +
                                (size_t)(bt * NTOK + chunk * KCHUNK + key) * 32 + half);
            uint4* dst = (uint4*)&Ks[key * 40 + half];
            dst[0] = src[0]; dst[1] = src[1];
        }
        // ---- stage V chunk transposed: threads 0..63, 2 keys each ----
        if (tid < KCHUNK / 2) {
            const int j0 = tid * 2;
            const u16* v0 = Vh + (size_t)h * HM + (size_t)(bt * NTOK + chunk * KCHUNK + j0) * 32;
            union U { uint4 q[4]; u32 w[16]; } ra, rb;
            #pragma unroll
            for (int i = 0; i < 4; ++i) {
                ra.q[i] = ((const uint4*)v0)[i];
                rb.q[i] = ((const uint4*)(v0 + 32))[i];
            }
            #pragma unroll
            for (int w = 0; w < 16; ++w) {
                u32 lo = __builtin_amdgcn_perm(rb.w[w], ra.w[w], 0x05040100u); // dim 2w
                u32 hi = __builtin_amdgcn_perm(rb.w[w], ra.w[w], 0x07060302u); // dim 2w+1
                *(u32*)&Vts[(2 * w)     * VSTR + j0] = lo;
                *(u32*)&Vts[(2 * w + 1) * VSTR + j0] = hi;
            }
        }
        __syncthreads();

        #pragma unroll
        for (int qbi = 0; qbi < 2; ++qbi) {
            const short8 A1 = (lane < 32) ? qv[qbi] : z8;  // dims 0..15
            const short8 A2 = (lane < 32) ? z8 : qv[qbi];  // dims 16..31

            #pragma unroll
            for (int kc = 0; kc < NKC; ++kc) {
                // ---- QK phase for step kc -> Pbuf[wv][kc&1] ----
                #pragma unroll
                for (int sub = 0; sub < 2; ++sub) {
                    const int key0 = kc * 32 + sub * 16;
                    short8 kf = *(const short8*)&Ks[(key0 + q16) * 40 + quad * 8];
                    // S^T: D[key=quad*4+r][q=q16]
                    __builtin_amdgcn_s_setprio(1);
                    f32x4 s1 = MFMA16(kf, A1, z4);
                    f32x4 s2 = MFMA16(kf, A2, z4);
                    __builtin_amdgcn_s_setprio(0);
                    float p0 = fexp2(s1[0]), p1 = fexp2(s1[1]);
                    float p2 = fexp2(s1[2]), p3 = fexp2(s1[3]);
                    l1[qbi] += (p0 + p1) + (p2 + p3);
                    uint2 w1; w1.x = pack_bf16(p0, p1); w1.y = pack_bf16(p2, p3);
                    *(uint2*)&Pbuf[wv][kc & 1][0][q16 * 40 + sub * 16 + quad * 4] = w1;
                    float r0 = fexp2(s2[0]), r1 = fexp2(s2[1]);
                    float r2 = fexp2(s2[2]), r3 = fexp2(s2[3]);
                    l2[qbi] += (r0 + r1) + (r2 + r3);
                    uint2 w2; w2.x = pack_bf16(r0, r1); w2.y = pack_bf16(r2, r3);
                    *(uint2*)&Pbuf[wv][kc & 1][1][q16 * 40 + sub * 16 + quad * 4] = w2;
                }
                LDS_FENCE();   // pin: QK writes of kc stay above PV reads below
                // ---- PV phase for step kc-1 <- Pbuf[wv][(kc-1)&1] ----
                if (kc > 0) {
                    const int pk = kc - 1;
                    const int pb = (kc - 1) & 1;
                    short8 pf1 = *(const short8*)&Pbuf[wv][pb][0][q16 * 40 + quad * 8];
                    short8 pf2 = *(const short8*)&Pbuf[wv][pb][1][q16 * 40 + quad * 8];
                    short8 vlo = *(const short8*)&Vts[q16        * VSTR + pk * 32 + quad * 8];
                    short8 vhi = *(const short8*)&Vts[(16 + q16) * VSTR + pk * 32 + quad * 8];
                    __builtin_amdgcn_s_setprio(1);
                    o1lo[qbi] = MFMA16(pf1, vlo, o1lo[qbi]);
                    o1hi[qbi] = MFMA16(pf1, vhi, o1hi[qbi]);
                    o2lo[qbi] = MFMA16(pf2, vlo, o2lo[qbi]);
                    o2hi[qbi] = MFMA16(pf2, vhi, o2hi[qbi]);
                    __builtin_amdgcn_s_setprio(0);
                }
                LDS_FENCE();   // pin: PV reads of kc-1 stay above QK writes of kc+1
            }
            // ---- PV tail for step NKC-1 ----
            {
                const int pk = NKC - 1;
                const int pb = (NKC - 1) & 1;
                short8 pf1 = *(const short8*)&Pbuf[wv][pb][0][q16 * 40 + quad * 8];
                short8 pf2 = *(const short8*)&Pbuf[wv][pb][1][q16 * 40 + quad * 8];
                short8 vlo = *(const short8*)&Vts[q16        * VSTR + pk * 32 + quad * 8];
                short8 vhi = *(const short8*)&Vts[(16 + q16) * VSTR + pk * 32 + quad * 8];
                __builtin_amdgcn_s_setprio(1);
                o1lo[qbi] = MFMA16(pf1, vlo, o1lo[qbi]);
                o1hi[qbi] = MFMA16(pf1, vhi, o1hi[qbi]);
                o2lo[qbi] = MFMA16(pf2, vlo, o2lo[qbi]);
                o2hi[qbi] = MFMA16(pf2, vhi, o2hi[qbi]);
                __builtin_amdgcn_s_setprio(0);
            }
            LDS_FENCE();       // pin: tail reads stay above next qbi's QK writes
        }
    }

    // ---- epilogue: softmax-normalize, diff combine, LayerNorm(32), store ----
    const float g_lo = gamma[q16],      g_hi = gamma[16 + q16];
    const float b_lo = beta[q16],       b_hi = beta[16 + q16];

    #pragma unroll
    for (int qbi = 0; qbi < 2; ++qbi) {
        float a = l1[qbi], b = l2[qbi];
        a += __shfl_xor(a, 16); a += __shfl_xor(a, 32);
        b += __shfl_xor(b, 16); b += __shfl_xor(b, 32);
        const float inv1 = 1.0f / a;    // valid for q = q16 (lanes 0..15 canonical)
        const float inv2 = 1.0f / b;
        #pragma unroll
        for (int r = 0; r < 4; ++r) {
            const float i1 = __shfl(inv1, quad * 4 + r);
            const float i2 = __shfl(inv2, quad * 4 + r);
            const float ylo = o1lo[qbi][r] * i1 - lam * (o2lo[qbi][r] * i2);
            const float yhi = o1hi[qbi][r] * i1 - lam * (o2hi[qbi][r] * i2);

            float s  = ylo + yhi;
            float s2 = ylo * ylo + yhi * yhi;
            #pragma unroll
            for (int off = 1; off < 16; off <<= 1) {
                s  += __shfl_xor(s,  off);
                s2 += __shfl_xor(s2, off);
            }
            const float mu   = s * (1.0f / 32.0f);
            const float var  = s2 * (1.0f / 32.0f) - mu * mu;
            const float rstd = rsqrtf(var + LN_EPS);

            const int row = bt * NTOK + qh * 128 + (qbi * 4 + wv) * 16 + quad * 4 + r;
            float* orow = out + (size_t)row * HID + h * 32;
            orow[q16]      = ((ylo - mu) * rstd * g_lo + b_lo) * ONE_MINUS_LI;
            orow[16 + q16] = ((yhi - mu) * rstd * g_hi + b_hi) * ONE_MINUS_LI;
        }
    }
}

// ---------------------------------------------------------------------------
extern "C" void kernel_launch(void* const* d_in, const int* in_sizes, int n_in,
                              void* d_out, int out_size, void* d_ws, size_t ws_size,
                              hipStream_t stream) {
    const float* x   = (const float*)d_in[0];
    const float* Wq  = (const float*)d_in[1];
    const float* Wk  = (const float*)d_in[2];
    const float* Wv  = (const float*)d_in[3];
    const float* lq1 = (const float*)d_in[4];
    const float* lk1 = (const float*)d_in[5];
    const float* lq2 = (const float*)d_in[6];
    const float* lk2 = (const float*)d_in[7];
    const float* gam = (const float*)d_in[8];
    const float* bet = (const float*)d_in[9];
    float* out = (float*)d_out;

    u16* ws = (u16*)d_ws;
    u16* Wt = ws;                 // 3 * 65536
    u16* Qh = Wt + 3 * 65536;     // head-major [8][16384][32]
    u16* Kh = Qh + TENS;
    u16* Vh = Kh + TENS;

    hipLaunchKernelGGL(prep_w, dim3(4, 4, 3), dim3(256), 0, stream, Wq, Wk, Wv, Wt);
    hipLaunchKernelGGL(proj_kernel, dim3(M_ROWS / 64, HID / 64), dim3(256), 0, stream,
                       x, Wt, Qh, Kh, Vh);
    hipLaunchKernelGGL(attn_kernel, dim3(4, 8, 32), dim3(256), 0, stream,
                       Qh, Kh, Vh, lq1, lk1, lq2, lk2, gam, bet, out);
}

// Round 12
// 130.644 us; speedup vs baseline: 1.0838x; 1.0120x over previous
//
#include <hip/hip_runtime.h>
#include <cmath>

typedef unsigned short u16;
typedef unsigned int   u32;
typedef __attribute__((ext_vector_type(8))) short short8;
typedef __attribute__((ext_vector_type(4))) float f32x4;

constexpr int BT    = 32;
constexpr int NTOK  = 512;
constexpr int DIM   = 256;
constexpr int HID   = 256;
constexpr int M_ROWS = BT * NTOK;            // 16384
constexpr int HM     = M_ROWS * 32;          // per-head elems in head-major QKV
constexpr size_t TENS = (size_t)M_ROWS * HID; // elems per full tensor
constexpr float LAMBDA_INIT  = 0.35550906759096927f;
constexpr float ONE_MINUS_LI = 0.6444909324090307f;
constexpr float LN_EPS = 1e-5f;
constexpr float QSCALE = 0.36067376022224085f;  // 0.25 * log2(e): fold into Q

// Session lessons:
//  R1: never force tight waves_per_eu (allocator spills).
//  R3: no by-ref-capturing lambdas in hot loops (SROA defeat -> scratch).
//  R4: cross-lane type-punned LDS flows need asm volatile("" ::: "memory").
//  R5: attn P-pipeline latency-neutral; attn issue/latency-bound.
//  R6/R8: proj K-loop staging/tiling changes all neutral.
//  R7: halving proj A-bytes neutral -> not traffic-bound.
//  R9: register async-STAGE in attn failed correctness; abandoned.
//  R10: setprio neutral. R11: LDS-bounce proj epilogue failed a harness
//      consistency check (unexplained) -> reverted to R10-proven epilogue.
//  R12 (this): rebalance attn V-transpose staging from 64 threads to all
//      256 (per-dword-quarter split; bit-identical staged values).
constexpr int KCHUNK = 128;

#define MFMA16(a, b, c) __builtin_amdgcn_mfma_f32_16x16x32_bf16((a), (b), (c), 0, 0, 0)
#define LDS_FENCE() asm volatile("" ::: "memory")

__device__ __forceinline__ u16 f2bf(float f) {   // RNE
    u32 u = __float_as_uint(f);
    return (u16)((u + 0x7FFFu + ((u >> 16) & 1u)) >> 16);
}

__device__ __forceinline__ float fexp2(float x) {
#if defined(__has_builtin) && __has_builtin(__builtin_amdgcn_exp2f)
    return __builtin_amdgcn_exp2f(x);
#else
    return exp2f(x);
#endif
}

// pack two f32 -> two bf16 (round-half-up) in one dword: a in low half
__device__ __forceinline__ u32 pack_bf16(float a, float b) {
    u32 ua = __float_as_uint(a) + 0x8000u;
    u32 ub = __float_as_uint(b) + 0x8000u;
    return __builtin_amdgcn_perm(ub, ua, 0x07060302u);
}

// ---------------------------------------------------------------------------
// prep_w: transpose + convert W (f32 [k][n]) -> Wt (bf16 [n][k]), 3 matrices
// ---------------------------------------------------------------------------
__global__ __launch_bounds__(256) void prep_w(const float* __restrict__ Wq,
                                              const float* __restrict__ Wk,
                                              const float* __restrict__ Wv,
                                              u16* __restrict__ Wt) {
    const float* W = (blockIdx.z == 0) ? Wq : (blockIdx.z == 1) ? Wk : Wv;
    u16* dst = Wt + (size_t)blockIdx.z * 65536;
    __shared__ float T[64][65];
    const int k0 = blockIdx.x * 64, n0 = blockIdx.y * 64;
    const int tr = threadIdx.x >> 4;
    const int tc = threadIdx.x & 15;
    #pragma unroll
    for (int i = 0; i < 4; ++i) {
        int row = tr + i * 16;
        float4 v = *(const float4*)&W[(size_t)(k0 + row) * HID + n0 + tc * 4];
        T[row][tc * 4 + 0] = v.x; T[row][tc * 4 + 1] = v.y;
        T[row][tc * 4 + 2] = v.z; T[row][tc * 4 + 3] = v.w;
    }
    __syncthreads();
    #pragma unroll
    for (int i = 0; i < 4; ++i) {
        int n = tr + i * 16;
        int k4 = tc * 4;
        uint2 pk;
        pk.x = (u32)f2bf(T[k4 + 0][n]) | ((u32)f2bf(T[k4 + 1][n]) << 16);
        pk.y = (u32)f2bf(T[k4 + 2][n]) | ((u32)f2bf(T[k4 + 3][n]) << 16);
        *(uint2*)&dst[(size_t)(n0 + n) * DIM + k0 + k4] = pk;
    }
}

// ---------------------------------------------------------------------------
// proj: fused QKV GEMM (exact R5/R10-proven structure). Stages x tile
// (f32->bf16 inline), multiplies by all 3 weights. Tile 64x64, BK=64,
// 4 waves each 32x32. Writes head-major bf16 [h][row][32]; Q scaled.
// ---------------------------------------------------------------------------
__global__ __launch_bounds__(256, 3) void proj_kernel(
    const float* __restrict__ x, const u16* __restrict__ Wt,
    u16* __restrict__ Qh, u16* __restrict__ Kh, u16* __restrict__ Vh)
{
    __shared__ u16 As[64 * 72];      // [m][k], stride 72 (144B, 16B aligned)
    __shared__ u16 Bs[3][64 * 72];   // [n][k] per z

    const int tid  = threadIdx.x;
    const int m0   = blockIdx.x * 64;
    const int n0   = blockIdx.y * 64;
    const int lane = tid & 63;
    const int wv   = tid >> 6;
    const int q16  = lane & 15;
    const int quad = lane >> 4;
    const int mw   = (wv >> 1) * 32;
    const int nw   = (wv & 1) * 32;

    const int sr = tid >> 2;          // 0..63 staging row
    const int sc = (tid & 3) * 16;    // 0,16,32,48 (u16 offset within 64-k)

    f32x4 acc[3][4];
    #pragma unroll
    for (int z = 0; z < 3; ++z)
        #pragma unroll
        for (int t = 0; t < 4; ++t)
            acc[z][t] = (f32x4){0.f, 0.f, 0.f, 0.f};

    for (int kk = 0; kk < DIM; kk += 64) {
        // A tile: load f32, convert to bf16
        {
            const float4* xs = (const float4*)&x[(size_t)(m0 + sr) * DIM + kk + sc];
            float4 g0 = xs[0], g1 = xs[1], g2 = xs[2], g3 = xs[3];
            uint4 o0, o1;
            o0.x = (u32)f2bf(g0.x) | ((u32)f2bf(g0.y) << 16);
            o0.y = (u32)f2bf(g0.z) | ((u32)f2bf(g0.w) << 16);
            o0.z = (u32)f2bf(g1.x) | ((u32)f2bf(g1.y) << 16);
            o0.w = (u32)f2bf(g1.z) | ((u32)f2bf(g1.w) << 16);
            o1.x = (u32)f2bf(g2.x) | ((u32)f2bf(g2.y) << 16);
            o1.y = (u32)f2bf(g2.z) | ((u32)f2bf(g2.w) << 16);
            o1.z = (u32)f2bf(g3.x) | ((u32)f2bf(g3.y) << 16);
            o1.w = (u32)f2bf(g3.z) | ((u32)f2bf(g3.w) << 16);
            *(uint4*)&As[sr * 72 + sc]     = o0;
            *(uint4*)&As[sr * 72 + sc + 8] = o1;
        }
        // B tiles (already bf16 in Wt)
        #pragma unroll
        for (int z = 0; z < 3; ++z) {
            const uint4* ws4 = (const uint4*)&Wt[(size_t)z * 65536 + (size_t)(n0 + sr) * DIM + kk + sc];
            *(uint4*)&Bs[z][sr * 72 + sc]     = ws4[0];
            *(uint4*)&Bs[z][sr * 72 + sc + 8] = ws4[1];
        }
        __syncthreads();
        #pragma unroll
        for (int kc = 0; kc < 2; ++kc) {
            short8 a0 = *(const short8*)&As[(mw +      q16) * 72 + kc * 32 + quad * 8];
            short8 a1 = *(const short8*)&As[(mw + 16 + q16) * 72 + kc * 32 + quad * 8];
            #pragma unroll
            for (int z = 0; z < 3; ++z) {
                short8 b0 = *(const short8*)&Bs[z][(nw +      q16) * 72 + kc * 32 + quad * 8];
                short8 b1 = *(const short8*)&Bs[z][(nw + 16 + q16) * 72 + kc * 32 + quad * 8];
                acc[z][0] = MFMA16(a0, b0, acc[z][0]);
                acc[z][1] = MFMA16(a0, b1, acc[z][1]);
                acc[z][2] = MFMA16(a1, b0, acc[z][2]);
                acc[z][3] = MFMA16(a1, b1, acc[z][3]);
            }
        }
        __syncthreads();
    }

    // epilogue: head-major store. C/D: col=lane&15, row=quad*4+reg
    const int hcol = (n0 + nw) >> 5;     // (n0+nw) is a multiple of 32
    #pragma unroll
    for (int z = 0; z < 3; ++z) {
        u16* C = (z == 0) ? Qh : (z == 1) ? Kh : Vh;
        u16* base = C + (size_t)hcol * HM;
        const float s = (z == 0) ? QSCALE : 1.0f;
        #pragma unroll
        for (int r = 0; r < 4; ++r) {
            const int row = m0 + mw + quad * 4 + r;
            base[(size_t)row * 32 + q16]             = f2bf(acc[z][0][r] * s);
            base[(size_t)row * 32 + q16 + 16]        = f2bf(acc[z][1][r] * s);
            base[(size_t)(row + 16) * 32 + q16]      = f2bf(acc[z][2][r] * s);
            base[(size_t)(row + 16) * 32 + q16 + 16] = f2bf(acc[z][3][r] * s);
        }
    }
}

// ---------------------------------------------------------------------------
// attn: transposed-QK MFMA attention + diff combine + LayerNorm.
// R10 structure (passed, 132.2us) with ONE change: V-transpose staging is
// spread across all 256 threads (per-dword-quarter split of each key pair)
// instead of 64 threads -- staged bytes bit-identical, phase ~4x shorter.
// ---------------------------------------------------------------------------
__global__ __launch_bounds__(256, 3) void attn_kernel(
    const u16* __restrict__ Qh, const u16* __restrict__ Kh, const u16* __restrict__ Vh,
    const float* __restrict__ lq1, const float* __restrict__ lk1,
    const float* __restrict__ lq2, const float* __restrict__ lk2,
    const float* __restrict__ gamma, const float* __restrict__ beta,
    float* __restrict__ out)
{
    constexpr int VSTR = KCHUNK + 8;
    constexpr int NKC  = KCHUNK / 32;        // 4 kc steps per chunk

    __shared__ u16 Ks[KCHUNK * 40];          // [key][dim] 10.0KB
    __shared__ u16 Vts[32 * VSTR];           // [dim][key]  8.5KB
    __shared__ u16 Pbuf[4][2][2][16 * 40];   // [wave][parity][matrix][q][key] 20.5KB

    const int qh  = blockIdx.x;   // 0..3 (128 q rows each)
    const int h   = blockIdx.y;   // 0..7
    const int bt  = blockIdx.z;   // 0..31
    const int tid = threadIdx.x;
    const int lane = tid & 63;
    const int wv   = tid >> 6;
    const int q16  = lane & 15;
    const int quad = lane >> 4;

    // lambda scalar (uniform path)
    float sa = 0.f, sb = 0.f;
    #pragma unroll
    for (int d = 0; d < 16; ++d) { sa += lq1[d] * lk1[d]; sb += lq2[d] * lk2[d]; }
    const float lam = __expf(sa) - __expf(sb) + LAMBDA_INIT;

    // Q B-fragments for this wave's two 16-row q blocks (pre-scaled at proj)
    short8 qv[2];
    #pragma unroll
    for (int qbi = 0; qbi < 2; ++qbi) {
        const int qrow = bt * NTOK + qh * 128 + (qbi * 4 + wv) * 16 + q16;
        qv[qbi] = *(const short8*)(Qh + (size_t)h * HM + (size_t)qrow * 32 + quad * 8);
    }

    const short8 z8 = {0, 0, 0, 0, 0, 0, 0, 0};
    const f32x4  z4 = {0.f, 0.f, 0.f, 0.f};

    f32x4 o1lo[2], o1hi[2], o2lo[2], o2hi[2];
    #pragma unroll
    for (int qbi = 0; qbi < 2; ++qbi) {
        o1lo[qbi] = z4; o1hi[qbi] = z4; o2lo[qbi] = z4; o2hi[qbi] = z4;
    }
    float l1[2] = {0.f, 0.f}, l2[2] = {0.f, 0.f};

    for (int chunk = 0; chunk < NTOK / KCHUNK; ++chunk) {
        if (chunk) __syncthreads();   // drain previous chunk's LDS reads
        // ---- stage K chunk: 128 rows, 2 threads per row (32B each, coalesced) ----
        {
            const int key  = tid >> 1;
            const int half = (tid & 1) * 16;   // u16 offset within 32-dim row
            const uint4* src = (const uint4*)(Kh + (size_t)h * HM +
                                (size_t)(bt * NTOK + chunk * KCHUNK + key) * 32 + half);
            uint4* dst = (uint4*)&Ks[key * 40 + half];
            dst[0] = src[0]; dst[1] = src[1];
        }
        // ---- stage V chunk transposed: ALL 256 threads, 1 key-pair-quarter
        //      each (pair = tid>>2, dword-quarter = tid&3). Bit-identical to
        //      the 64-thread version; 4x shorter critical path. ----
        {
            const int pr = tid >> 2;          // key pair 0..63
            const int qd = tid & 3;           // dword quarter 0..3
            const int j0 = pr * 2;
            const u16* v0 = Vh + (size_t)h * HM + (size_t)(bt * NTOK + chunk * KCHUNK + j0) * 32;
            union U { uint4 q4; u32 w[4]; } ra, rb;
            ra.q4 = ((const uint4*)v0)[qd];        // key j0,  dims 8qd..8qd+7
            rb.q4 = ((const uint4*)(v0 + 32))[qd]; // key j0+1, same dims
            #pragma unroll
            for (int k = 0; k < 4; ++k) {
                const int w = qd * 4 + k;          // dword index 0..15 (dims 2w,2w+1)
                u32 lo = __builtin_amdgcn_perm(rb.w[k], ra.w[k], 0x05040100u); // dim 2w
                u32 hi = __builtin_amdgcn_perm(rb.w[k], ra.w[k], 0x07060302u); // dim 2w+1
                *(u32*)&Vts[(2 * w)     * VSTR + j0] = lo;
                *(u32*)&Vts[(2 * w + 1) * VSTR + j0] = hi;
            }
        }
        __syncthreads();

        #pragma unroll
        for (int qbi = 0; qbi < 2; ++qbi) {
            const short8 A1 = (lane < 32) ? qv[qbi] : z8;  // dims 0..15
            const short8 A2 = (lane < 32) ? z8 : qv[qbi];  // dims 16..31

            #pragma unroll
            for (int kc = 0; kc < NKC; ++kc) {
                // ---- QK phase for step kc -> Pbuf[wv][kc&1] ----
                #pragma unroll
                for (int sub = 0; sub < 2; ++sub) {
                    const int key0 = kc * 32 + sub * 16;
                    short8 kf = *(const short8*)&Ks[(key0 + q16) * 40 + quad * 8];
                    // S^T: D[key=quad*4+r][q=q16]
                    __builtin_amdgcn_s_setprio(1);
                    f32x4 s1 = MFMA16(kf, A1, z4);
                    f32x4 s2 = MFMA16(kf, A2, z4);
                    __builtin_amdgcn_s_setprio(0);
                    float p0 = fexp2(s1[0]), p1 = fexp2(s1[1]);
                    float p2 = fexp2(s1[2]), p3 = fexp2(s1[3]);
                    l1[qbi] += (p0 + p1) + (p2 + p3);
                    uint2 w1; w1.x = pack_bf16(p0, p1); w1.y = pack_bf16(p2, p3);
                    *(uint2*)&Pbuf[wv][kc & 1][0][q16 * 40 + sub * 16 + quad * 4] = w1;
                    float r0 = fexp2(s2[0]), r1 = fexp2(s2[1]);
                    float r2 = fexp2(s2[2]), r3 = fexp2(s2[3]);
                    l2[qbi] += (r0 + r1) + (r2 + r3);
                    uint2 w2; w2.x = pack_bf16(r0, r1); w2.y = pack_bf16(r2, r3);
                    *(uint2*)&Pbuf[wv][kc & 1][1][q16 * 40 + sub * 16 + quad * 4] = w2;
                }
                LDS_FENCE();   // pin: QK writes of kc stay above PV reads below
                // ---- PV phase for step kc-1 <- Pbuf[wv][(kc-1)&1] ----
                if (kc > 0) {
                    const int pk = kc - 1;
                    const int pb = (kc - 1) & 1;
                    short8 pf1 = *(const short8*)&Pbuf[wv][pb][0][q16 * 40 + quad * 8];
                    short8 pf2 = *(const short8*)&Pbuf[wv][pb][1][q16 * 40 + quad * 8];
                    short8 vlo = *(const short8*)&Vts[q16        * VSTR + pk * 32 + quad * 8];
                    short8 vhi = *(const short8*)&Vts[(16 + q16) * VSTR + pk * 32 + quad * 8];
                    __builtin_amdgcn_s_setprio(1);
                    o1lo[qbi] = MFMA16(pf1, vlo, o1lo[qbi]);
                    o1hi[qbi] = MFMA16(pf1, vhi, o1hi[qbi]);
                    o2lo[qbi] = MFMA16(pf2, vlo, o2lo[qbi]);
                    o2hi[qbi] = MFMA16(pf2, vhi, o2hi[qbi]);
                    __builtin_amdgcn_s_setprio(0);
                }
                LDS_FENCE();   // pin: PV reads of kc-1 stay above QK writes of kc+1
            }
            // ---- PV tail for step NKC-1 ----
            {
                const int pk = NKC - 1;
                const int pb = (NKC - 1) & 1;
                short8 pf1 = *(const short8*)&Pbuf[wv][pb][0][q16 * 40 + quad * 8];
                short8 pf2 = *(const short8*)&Pbuf[wv][pb][1][q16 * 40 + quad * 8];
                short8 vlo = *(const short8*)&Vts[q16        * VSTR + pk * 32 + quad * 8];
                short8 vhi = *(const short8*)&Vts[(16 + q16) * VSTR + pk * 32 + quad * 8];
                __builtin_amdgcn_s_setprio(1);
                o1lo[qbi] = MFMA16(pf1, vlo, o1lo[qbi]);
                o1hi[qbi] = MFMA16(pf1, vhi, o1hi[qbi]);
                o2lo[qbi] = MFMA16(pf2, vlo, o2lo[qbi]);
                o2hi[qbi] = MFMA16(pf2, vhi, o2hi[qbi]);
                __builtin_amdgcn_s_setprio(0);
            }
            LDS_FENCE();       // pin: tail reads stay above next qbi's QK writes
        }
    }

    // ---- epilogue: softmax-normalize, diff combine, LayerNorm(32), store ----
    const float g_lo = gamma[q16],      g_hi = gamma[16 + q16];
    const float b_lo = beta[q16],       b_hi = beta[16 + q16];

    #pragma unroll
    for (int qbi = 0; qbi < 2; ++qbi) {
        float a = l1[qbi], b = l2[qbi];
        a += __shfl_xor(a, 16); a += __shfl_xor(a, 32);
        b += __shfl_xor(b, 16); b += __shfl_xor(b, 32);
        const float inv1 = 1.0f / a;    // valid for q = q16 (lanes 0..15 canonical)
        const float inv2 = 1.0f / b;
        #pragma unroll
        for (int r = 0; r < 4; ++r) {
            const float i1 = __shfl(inv1, quad * 4 + r);
            const float i2 = __shfl(inv2, quad * 4 + r);
            const float ylo = o1lo[qbi][r] * i1 - lam * (o2lo[qbi][r] * i2);
            const float yhi = o1hi[qbi][r] * i1 - lam * (o2hi[qbi][r] * i2);

            float s  = ylo + yhi;
            float s2 = ylo * ylo + yhi * yhi;
            #pragma unroll
            for (int off = 1; off < 16; off <<= 1) {
                s  += __shfl_xor(s,  off);
                s2 += __shfl_xor(s2, off);
            }
            const float mu   = s * (1.0f / 32.0f);
            const float var  = s2 * (1.0f / 32.0f) - mu * mu;
            const float rstd = rsqrtf(var + LN_EPS);

            const int row = bt * NTOK + qh * 128 + (qbi * 4 + wv) * 16 + quad * 4 + r;
            float* orow = out + (size_t)row * HID + h * 32;
            orow[q16]      = ((ylo - mu) * rstd * g_lo + b_lo) * ONE_MINUS_LI;
            orow[16 + q16] = ((yhi - mu) * rstd * g_hi + b_hi) * ONE_MINUS_LI;
        }
    }
}

// ---------------------------------------------------------------------------
extern "C" void kernel_launch(void* const* d_in, const int* in_sizes, int n_in,
                              void* d_out, int out_size, void* d_ws, size_t ws_size,
                              hipStream_t stream) {
    const float* x   = (const float*)d_in[0];
    const float* Wq  = (const float*)d_in[1];
    const float* Wk  = (const float*)d_in[2];
    const float* Wv  = (const float*)d_in[3];
    const float* lq1 = (const float*)d_in[4];
    const float* lk1 = (const float*)d_in[5];
    const float* lq2 = (const float*)d_in[6];
    const float* lk2 = (const float*)d_in[7];
    const float* gam = (const float*)d_in[8];
    const float* bet = (const float*)d_in[9];
    float* out = (float*)d_out;

    u16* ws = (u16*)d_ws;
    u16* Wt = ws;                 // 3 * 65536
    u16* Qh = Wt + 3 * 65536;     // head-major [8][16384][32]
    u16* Kh = Qh + TENS;
    u16* Vh = Kh + TENS;

    hipLaunchKernelGGL(prep_w, dim3(4, 4, 3), dim3(256), 0, stream, Wq, Wk, Wv, Wt);
    hipLaunchKernelGGL(proj_kernel, dim3(M_ROWS / 64, HID / 64), dim3(256), 0, stream,
                       x, Wt, Qh, Kh, Vh);
    hipLaunchKernelGGL(attn_kernel, dim3(4, 8, 32), dim3(256), 0, stream,
                       Qh, Kh, Vh, lq1, lk1, lq2, lk2, gam, bet, out);
}